// Round 12
// baseline (2129.605 us; speedup 1.0000x reference)
//
#include <hip/hip_runtime.h>
#include <hip/hip_bf16.h>
#include <math.h>

typedef __hip_bfloat16 bf16;
typedef __attribute__((ext_vector_type(8))) short s8v;
typedef __attribute__((ext_vector_type(4))) float f4v;

// Problem constants (MambaEncoder: L=2, B=2, S=1024, D=512) — f32 in, f32 out.
#define B_ 2
#define S_ 1024
#define D_ 512
#define DH_ 256
#define DI_ 512
#define N_ 16
#define M_ 2048
#define M2_ 4096
#define T_ 16     // scan chunk length (register-preloaded)
#define CN_ 64    // chunks per sequence
#define NCP_ 640  // combined dt|B|C GEMM N (512 dt + 16 B + 16 C + 96 pad)
#define NB_ 512   // persistent grid blocks (2/CU guaranteed by launch_bounds)

#define IPW_N (2*512*512)
#define INW_N (4*1024*256)
#define OUTW_N (4*256*512)
#define OPW_N (2*512*512)
#define PREP_R0 ((IPW_N+INW_N+OUTW_N+OPW_N)/4)
#define PREP_R1 (4*NCP_*512)
#define PREP_R2 ((M_*D_)/4)
#define PREP_TOT (PREP_R0+PREP_R1+PREP_R2)

__device__ __forceinline__ float softplus_fast(float v) {
  return (v > 15.f) ? v : __logf(1.f + __expf(v));
}

// Single-use grid barrier (slot idx). Counters zeroed by hipMemsetAsync.
// Bounded spin: worst case ~1.5s then falls through (absmax will catch).
__device__ __forceinline__ void gsync(unsigned* bar, int idx) {
  __syncthreads();
  if (threadIdx.x == 0) {
    __threadfence();
    unsigned* p = bar + idx * 16;
    __hip_atomic_fetch_add(p, 1u, __ATOMIC_ACQ_REL, __HIP_MEMORY_SCOPE_AGENT);
    for (long it = 0; it < (1L << 22); ++it) {
      if (__hip_atomic_load(p, __ATOMIC_ACQUIRE, __HIP_MEMORY_SCOPE_AGENT) >= (unsigned)NB_)
        break;
      __builtin_amdgcn_s_sleep(16);
    }
    __threadfence();
  }
  __syncthreads();
}

// ---------------------------------------------------------------------------
// Phase bodies (verbatim logic from the proven standalone kernels).

__device__ __forceinline__ void prep_item(
    int i,
    const float* ipW, const float* inW, const float* outW, const float* opW,
    const float* dtW, const float* xprojW, const float* x,
    bf16* ipWb, bf16* inWb, bf16* outWb, bf16* opWb, bf16* Wcomb, bf16* xb) {
  if (i < PREP_R0) {
    int e = i * 4;
    const float* s; bf16* dst; int off;
    if (e < IPW_N)                       { s = ipW;  dst = ipWb;  off = e; }
    else if (e < IPW_N + INW_N)          { s = inW;  dst = inWb;  off = e - IPW_N; }
    else if (e < IPW_N + INW_N + OUTW_N) { s = outW; dst = outWb; off = e - IPW_N - INW_N; }
    else                                 { s = opW;  dst = opWb;  off = e - IPW_N - INW_N - OUTW_N; }
    float4 v = *(const float4*)&s[off];
    dst[off + 0] = __float2bfloat16(v.x);
    dst[off + 1] = __float2bfloat16(v.y);
    dst[off + 2] = __float2bfloat16(v.z);
    dst[off + 3] = __float2bfloat16(v.w);
  } else if (i < PREP_R0 + PREP_R1) {
    int idx = i - PREP_R0;
    int k = idx & 511;
    int row = (idx >> 9) % NCP_;
    int wi = idx / (NCP_ * 512);
    float v = 0.f;
    if (row < 512) {
      const float* dw = dtW + (size_t)wi * 512 * 16 + row * 16;
      const float* xw = xprojW + (size_t)wi * 48 * 512;
#pragma unroll
      for (int r = 0; r < 16; r++) v += dw[r] * xw[r * 512 + k];
    } else if (row < 544) {
      v = xprojW[(size_t)wi * 48 * 512 + (16 + row - 512) * 512 + k];
    }
    Wcomb[idx] = __float2bfloat16(v);
  } else if (i < PREP_TOT) {
    int e = (i - PREP_R0 - PREP_R1) * 4;
    float4 v = *(const float4*)&x[e];
    xb[e + 0] = __float2bfloat16(v.x);
    xb[e + 1] = __float2bfloat16(v.y);
    xb[e + 2] = __float2bfloat16(v.z);
    xb[e + 3] = __float2bfloat16(v.w);
  }
}

// 64x64 GEMM tile. ep0: +bias/+res; ep3: ip+split(flip); ep4: op+concat.
__device__ __forceinline__ void gemm64_tile(
    const bf16* A, const float* Af, const bf16* W, long Wstr,
    const float* bias, int bstr, const float* res,
    float* C, bf16* Cb, int ldc, int K, int ep, int bm, int bn,
    short (*As)[40], short (*Ws)[40]) {
  const int seg = bm >> 11;
  const bf16* Wp = W + (size_t)seg * Wstr;
  const float* bp = bias ? bias + (size_t)seg * bstr : nullptr;
  const int tid = threadIdx.x;
  const int wave = tid >> 6, lane = tid & 63;
  const int q = lane >> 4, l15 = lane & 15;
  const int trow = tid >> 2, tcol = (tid & 3) * 8;

  f4v acc[4];
#pragma unroll
  for (int s = 0; s < 4; s++) acc[s] = (f4v){0.f, 0.f, 0.f, 0.f};

  for (int k0 = 0; k0 < K; k0 += 32) {
    if (ep == 4) {
      int ck = k0 + tcol;
      const float* src = (ck < 256)
          ? Af + (size_t)(bm + trow) * 256 + ck
          : Af + (size_t)M_ * 256 + (size_t)((bm + trow) ^ 1023) * 256 + (ck - 256);
      float4 f0 = *(const float4*)src;
      float4 f1 = *(const float4*)(src + 4);
      float fv[8] = {f0.x, f0.y, f0.z, f0.w, f1.x, f1.y, f1.z, f1.w};
      short tmp[8];
#pragma unroll
      for (int i = 0; i < 8; i++) {
        bf16 b = __float2bfloat16(fv[i]);
        tmp[i] = *(short*)&b;
      }
      *(uint4*)&As[trow][tcol] = *(uint4*)tmp;
    } else {
      *(uint4*)&As[trow][tcol] = *(const uint4*)&A[(size_t)(bm + trow) * K + k0 + tcol];
    }
    *(uint4*)&Ws[trow][tcol] = *(const uint4*)&Wp[(size_t)(bn + trow) * K + k0 + tcol];
    __syncthreads();
    s8v bfrag = *(const s8v*)&Ws[wave * 16 + l15][q * 8];
#pragma unroll
    for (int s = 0; s < 4; s++) {
      s8v afrag = *(const s8v*)&As[s * 16 + l15][q * 8];
      acc[s] = __builtin_amdgcn_mfma_f32_16x16x32_bf16(afrag, bfrag, acc[s], 0, 0, 0);
    }
    __syncthreads();
  }
  const int col = bn + wave * 16 + l15;
#pragma unroll
  for (int s = 0; s < 4; s++) {
#pragma unroll
    for (int r = 0; r < 4; r++) {
      int row = bm + s * 16 + q * 4 + r;
      float v = acc[s][r];
      if (ep == 0) {
        if (bp) v += bp[col];
        if (res) v += res[(size_t)row * ldc + col];
        C[(size_t)row * ldc + col] = v;
      } else if (ep == 3) {
        v += bp[col];
        if (col < 256)
          C[(size_t)row * 256 + col] = v;
        else
          C[(size_t)M_ * 256 + (size_t)(row ^ 1023) * 256 + (col - 256)] = v;
      } else {  // ep4
        v += bp[col];
        C[(size_t)row * 512 + col] = v;
        Cb[(size_t)row * 512 + col] = __float2bfloat16(v);
      }
    }
  }
}

// 64x128 GEMM tile. ep1: bf16 out; ep2: softplus(dt)|B|C.
__device__ __forceinline__ void mgX_tile(
    const bf16* A, const bf16* W, long Wstr,
    const float* bias, int bstr,
    float* C, bf16* Cb, int ldc, int K, int ep, int bm, int bn,
    short (*As)[40], short (*Ws)[40]) {
  const int seg = bm >> 11;
  const bf16* Wp = W + (size_t)seg * Wstr;
  const float* bp = bias ? bias + (size_t)seg * bstr : nullptr;
  const int tid = threadIdx.x;
  const int wave = tid >> 6, lane = tid & 63;
  const int q = lane >> 4, l15 = lane & 15;
  const int wc = wave * 32;
  const int arow = tid >> 2, acol = (tid & 3) * 8;
  const int wrow = tid >> 1, wcol = (tid & 1) * 16;

  f4v acc[4][2];
#pragma unroll
  for (int s = 0; s < 4; s++)
#pragma unroll
    for (int j = 0; j < 2; j++) acc[s][j] = (f4v){0.f, 0.f, 0.f, 0.f};

  for (int k0 = 0; k0 < K; k0 += 32) {
    *(uint4*)&As[arow][acol] = *(const uint4*)&A[(size_t)(bm + arow) * K + k0 + acol];
    const bf16* wsrc = &Wp[(size_t)(bn + wrow) * K + k0 + wcol];
    *(uint4*)&Ws[wrow][wcol] = *(const uint4*)wsrc;
    *(uint4*)&Ws[wrow][wcol + 8] = *(const uint4*)(wsrc + 8);
    __syncthreads();
    s8v af[4], bf[2];
#pragma unroll
    for (int s = 0; s < 4; s++) af[s] = *(const s8v*)&As[s * 16 + l15][q * 8];
#pragma unroll
    for (int j = 0; j < 2; j++) bf[j] = *(const s8v*)&Ws[wc + j * 16 + l15][q * 8];
#pragma unroll
    for (int s = 0; s < 4; s++)
#pragma unroll
      for (int j = 0; j < 2; j++)
        acc[s][j] = __builtin_amdgcn_mfma_f32_16x16x32_bf16(af[s], bf[j], acc[s][j], 0, 0, 0);
    __syncthreads();
  }
#pragma unroll
  for (int j = 0; j < 2; j++) {
    int col = bn + wc + j * 16 + l15;
#pragma unroll
    for (int s = 0; s < 4; s++) {
      int row0 = bm + s * 16 + q * 4;
#pragma unroll
      for (int r = 0; r < 4; r++) {
        float v = acc[s][j][r];
        if (ep == 1) {
          Cb[(size_t)(row0 + r) * ldc + col] = __float2bfloat16(v);
        } else {
          if (col < 512) v = softplus_fast(v + bp[col]);
          C[(size_t)(row0 + r) * ldc + col] = v;
        }
      }
    }
  }
}

// One LayerNorm row (256 threads cooperate).
__device__ __forceinline__ void ln_row(
    int row, const float* X, const float* g, const float* bta, int gstr,
    void* Y, int C, int out_bf16, float* r1, float* r2) {
  const int sel = (row >= M_) ? gstr : 0;
  const float* xr = X + (size_t)row * C;
  const int tid = threadIdx.x;
  const int per = C >> 8;
  float vals[2];
  float sum = 0.f, sumsq = 0.f;
  for (int i = 0; i < per; i++) {
    float v = xr[tid + i * 256];
    vals[i] = v;
    sum += v;
    sumsq += v * v;
  }
#pragma unroll
  for (int off = 1; off < 64; off <<= 1) {
    sum += __shfl_xor(sum, off, 64);
    sumsq += __shfl_xor(sumsq, off, 64);
  }
  int wid = tid >> 6, lane = tid & 63;
  if (lane == 0) { r1[wid] = sum; r2[wid] = sumsq; }
  __syncthreads();
  if (tid == 0) {
    float a = 0.f, c2 = 0.f;
    for (int w = 0; w < 4; w++) { a += r1[w]; c2 += r2[w]; }
    r1[0] = a; r2[0] = c2;
  }
  __syncthreads();
  float mean = r1[0] / (float)C;
  float var = r2[0] / (float)C - mean * mean;
  float rstd = rsqrtf(var + 1e-5f);
  __syncthreads();  // protect r1/r2 reuse on next row
  for (int i = 0; i < per; i++) {
    int c = tid + i * 256;
    float y = (vals[i] - mean) * rstd * g[sel + c] + bta[sel + c];
    if (out_bf16)
      ((bf16*)Y)[(size_t)row * C + c] = __float2bfloat16(y);
    else
      ((float*)Y)[(size_t)row * C + c] = y;
  }
}

__device__ __forceinline__ void conv_item(
    int idx, const bf16* xz, const float* convW, const float* convB,
    bf16* outb) {
  int d = idx & (DI_ - 1);
  int row = idx >> 9;
  int seg = row >> 11;
  int t = row & (S_ - 1);
  const float* w = convW + seg * DI_ * 4;
  float acc = convB[seg * DI_ + d];
#pragma unroll
  for (int k = 0; k < 4; k++) {
    int dt_ = k - 3;
    if (t + dt_ >= 0)
      acc += w[d * 4 + k] * __bfloat162float(xz[(size_t)(row + dt_) * 1024 + d]);
  }
  float s = acc / (1.f + __expf(-acc));
  outb[idx] = __float2bfloat16(s);
}

__device__ __forceinline__ void scanA_block(
    int blk, const float* dtbc, const bf16* xcb, const float* A_log,
    float* P, float* hend, float (*Bs)[16]) {
  const int half = blk & 1;
  const int c = (blk >> 1) & (CN_ - 1);
  const int s = blk >> 7;
  const int dir = s >> 1;
  const int d = half * 256 + threadIdx.x;
  const int r0 = s * S_ + c * T_;
  for (int i = threadIdx.x; i < T_ * 16; i += 256) {
    int t = i >> 4, n = i & 15;
    Bs[t][n] = dtbc[(size_t)(r0 + t) * NCP_ + 512 + n];
  }
  float Av[16];
#pragma unroll
  for (int n = 0; n < 16; n++) Av[n] = -__expf(A_log[dir * DI_ * 16 + d * 16 + n]);
  float dtv[T_], xv[T_];
#pragma unroll
  for (int t = 0; t < T_; t++) {
    size_t row = (size_t)(r0 + t);
    dtv[t] = dtbc[row * NCP_ + d];
    xv[t]  = __bfloat162float(xcb[row * 512 + d]);
  }
  __syncthreads();
  float h[16], Pr[16];
#pragma unroll
  for (int n = 0; n < 16; n++) { h[n] = 0.f; Pr[n] = 1.f; }
#pragma unroll
  for (int t = 0; t < T_; t++) {
    float dtx = dtv[t] * xv[t];
#pragma unroll
    for (int n = 0; n < 16; n++) {
      float a = __expf(dtv[t] * Av[n]);
      h[n] = a * h[n] + dtx * Bs[t][n];
      Pr[n] *= a;
    }
  }
  size_t base = (((size_t)s * CN_ + c) * 16) * 512 + d;
#pragma unroll
  for (int n = 0; n < 16; n++) {
    P[base + (size_t)n * 512] = Pr[n];
    hend[base + (size_t)n * 512] = h[n];
  }
  __syncthreads();  // protect Bs reuse
}

__device__ __forceinline__ void scanB_item(
    int idx, const float* P, const float* hend, float* Hinit) {
  int d = idx & 511;
  int n = (idx >> 9) & 15;
  int s = idx >> 13;
  float H = 0.f;
  for (int c = 0; c < CN_; c++) {
    size_t o = (((size_t)s * CN_ + c) * 16 + n) * 512 + d;
    float p = P[o];
    float he = hend[o];
    Hinit[o] = H;
    H = p * H + he;
  }
}

__device__ __forceinline__ void scanC_block(
    int blk, const float* dtbc, const bf16* xz, const bf16* xcb,
    const float* A_log, const float* Dp, const float* Hinit, bf16* ybf,
    float (*Bs)[16], float (*Cs)[16]) {
  const int half = blk & 1;
  const int c = (blk >> 1) & (CN_ - 1);
  const int s = blk >> 7;
  const int dir = s >> 1;
  const int d = half * 256 + threadIdx.x;
  const int r0 = s * S_ + c * T_;
  for (int i = threadIdx.x; i < T_ * 16; i += 256) {
    int t = i >> 4, n = i & 15;
    size_t ro = (size_t)(r0 + t) * NCP_;
    Bs[t][n] = dtbc[ro + 512 + n];
    Cs[t][n] = dtbc[ro + 528 + n];
  }
  float Av[16];
#pragma unroll
  for (int n = 0; n < 16; n++) Av[n] = -__expf(A_log[dir * DI_ * 16 + d * 16 + n]);
  float Dd = Dp[dir * DI_ + d];
  float dtv[T_], xv[T_], zv[T_];
#pragma unroll
  for (int t = 0; t < T_; t++) {
    size_t row = (size_t)(r0 + t);
    dtv[t] = dtbc[row * NCP_ + d];
    xv[t]  = __bfloat162float(xcb[row * 512 + d]);
    zv[t]  = __bfloat162float(xz[row * 1024 + 512 + d]);
  }
  float h[16];
  size_t hbase = (((size_t)s * CN_ + c) * 16) * 512 + d;
#pragma unroll
  for (int n = 0; n < 16; n++) h[n] = Hinit[hbase + (size_t)n * 512];
  __syncthreads();
#pragma unroll
  for (int t = 0; t < T_; t++) {
    float dtx = dtv[t] * xv[t];
    float acc = 0.f;
#pragma unroll
    for (int n = 0; n < 16; n++) {
      float a = __expf(dtv[t] * Av[n]);
      h[n] = a * h[n] + dtx * Bs[t][n];
      acc += h[n] * Cs[t][n];
    }
    float sil = zv[t] / (1.f + __expf(-zv[t]));
    ybf[(size_t)(r0 + t) * 512 + d] = __float2bfloat16((acc + xv[t] * Dd) * sil);
  }
  __syncthreads();
}

// ---------------------------------------------------------------------------
// The megakernel: all phases, separated by grid barriers.
__global__ __launch_bounds__(256, 2) void k_mega(
    const float* x, const float* ln_g, const float* ln_b,
    const float* inW, const float* convW, const float* convB,
    const float* xprojW, const float* dtW, const float* dtB,
    const float* A_log, const float* Dp, const float* outW,
    const float* ipW, const float* ipB, const float* opW, const float* opB,
    const float* fln_g, const float* fln_b, float* out,
    float* h_cur, float* u_f, float* dtbc2, float* Pbuf, float* hend,
    bf16* xz2b, bf16* xb, bf16* xnb2, bf16* xcvb2, bf16* ybf2,
    bf16* ipWb, bf16* inWb, bf16* outWb, bf16* opWb, bf16* Wcomb,
    unsigned* bar) {
  __shared__ short As[64][40];
  __shared__ short Ws[128][40];
  __shared__ float Bs[16][16], Cs[16][16];
  __shared__ float r1[4], r2[4];
  float* Hinit = Pbuf;  // alias (scanB read-then-write per element)
  int bi = 0;
  const int gtid = blockIdx.x * 256 + threadIdx.x;

  // P0: prep
  for (int i = gtid; i < PREP_TOT; i += NB_ * 256)
    prep_item(i, ipW, inW, outW, opW, dtW, xprojW, x,
              ipWb, inWb, outWb, opWb, Wcomb, xb);
  gsync(bar, bi++);

  for (int li = 0; li < 2; li++) {
    // P1: ip + split (256 tiles)
    for (int t = blockIdx.x; t < 256; t += NB_)
      gemm64_tile(xb, nullptr, ipWb + (size_t)li * D_ * D_, 0,
                  ipB + (size_t)li * D_, 0, nullptr, u_f, nullptr, 256, D_, 3,
                  (t >> 3) * 64, (t & 7) * 64, As, (short(*)[40])Ws);
    gsync(bar, bi++);
    // P2: LN (4096 rows)
    for (int row = blockIdx.x; row < M2_; row += NB_)
      ln_row(row, u_f, ln_g + li * 2 * DH_, ln_b + li * 2 * DH_, DH_,
             (void*)xnb2, DH_, 1, r1, r2);
    gsync(bar, bi++);
    // P3: in-proj (512 tiles, 64x128)
    for (int t = blockIdx.x; t < 512; t += NB_)
      mgX_tile(xnb2, inWb + (size_t)li * 2 * 1024 * DH_, (long)1024 * DH_,
               nullptr, 0, nullptr, xz2b, 1024, DH_, 1,
               (t >> 3) * 64, (t & 7) * 128, As, Ws);
    gsync(bar, bi++);
    // P4: conv + silu
    for (int i = gtid; i < M2_ * DI_; i += NB_ * 256)
      conv_item(i, xz2b, convW + li * 2 * DI_ * 4, convB + li * 2 * DI_, xcvb2);
    gsync(bar, bi++);
    // P5: dtbc (320 tiles, 64x128)
    for (int t = blockIdx.x; t < 320; t += NB_)
      mgX_tile(xcvb2, Wcomb + (size_t)li * 2 * NCP_ * 512, (long)NCP_ * 512,
               dtB + li * 2 * DI_, DI_, dtbc2, nullptr, NCP_, 512, 2,
               (t / 5) * 64, (t % 5) * 128, As, Ws);
    gsync(bar, bi++);
    // P6: scanA (512 virtual blocks)
    for (int v = blockIdx.x; v < 512; v += NB_)
      scanA_block(v, dtbc2, xcvb2, A_log + (size_t)li * 2 * DI_ * N_,
                  Pbuf, hend, Bs);
    gsync(bar, bi++);
    // P7: scanB (32768 items)
    for (int i = gtid; i < 4 * 16 * 512; i += NB_ * 256)
      scanB_item(i, Pbuf, hend, Hinit);
    gsync(bar, bi++);
    // P8: scanC (512 virtual blocks)
    for (int v = blockIdx.x; v < 512; v += NB_)
      scanC_block(v, dtbc2, xz2b, xcvb2, A_log + (size_t)li * 2 * DI_ * N_,
                  Dp + (size_t)li * 2 * DI_, Hinit, ybf2, Bs, Cs);
    gsync(bar, bi++);
    // P9: out-proj + residual (256 tiles)
    for (int t = blockIdx.x; t < 256; t += NB_)
      gemm64_tile(ybf2, nullptr, outWb + (size_t)li * 2 * DH_ * DI_,
                  (long)DH_ * DI_, nullptr, 0, u_f, u_f, nullptr, 256, DI_, 0,
                  (t >> 2) * 64, (t & 3) * 64, As, (short(*)[40])Ws);
    gsync(bar, bi++);
    // P10: op + concat(+flip) (256 tiles)
    for (int t = blockIdx.x; t < 256; t += NB_)
      gemm64_tile(nullptr, u_f, opWb + (size_t)li * D_ * D_, 0,
                  opB + (size_t)li * D_, 0, nullptr, h_cur, xb, 512, D_, 4,
                  (t >> 3) * 64, (t & 7) * 64, As, (short(*)[40])Ws);
    gsync(bar, bi++);
  }
  // P11: final LN (2048 rows)
  for (int row = blockIdx.x; row < M_; row += NB_)
    ln_row(row, h_cur, fln_g, fln_b, 0, (void*)out, D_, 0, r1, r2);
}

// ---------------------------------------------------------------------------
extern "C" void kernel_launch(void* const* d_in, const int* in_sizes, int n_in,
                              void* d_out, int out_size, void* d_ws, size_t ws_size,
                              hipStream_t stream) {
  const float* x     = (const float*)d_in[0];
  const float* ln_g  = (const float*)d_in[1];
  const float* ln_b  = (const float*)d_in[2];
  const float* inW   = (const float*)d_in[3];
  const float* convW = (const float*)d_in[4];
  const float* convB = (const float*)d_in[5];
  const float* xprojW= (const float*)d_in[6];
  const float* dtW   = (const float*)d_in[7];
  const float* dtB   = (const float*)d_in[8];
  const float* A_log = (const float*)d_in[9];
  const float* Dp    = (const float*)d_in[10];
  const float* outW  = (const float*)d_in[11];
  const float* ipW   = (const float*)d_in[12];
  const float* ipB   = (const float*)d_in[13];
  const float* opW   = (const float*)d_in[14];
  const float* opB   = (const float*)d_in[15];
  const float* fln_g = (const float*)d_in[16];
  const float* fln_b = (const float*)d_in[17];
  float* out = (float*)d_out;

  // ---- workspace: barrier counters first (64B-aligned), then buffers ----
  unsigned* bar = (unsigned*)d_ws;
  float* w = (float*)((char*)d_ws + 4096);
  float* h_cur = w;  w += (size_t)M_ * D_;
  float* u_f   = w;  w += (size_t)M2_ * DH_;
  float* dtbc2 = w;  w += (size_t)M2_ * NCP_;
  float* Pbuf  = w;  w += (size_t)4 * CN_ * 16 * 512;
  float* hend  = w;  w += (size_t)4 * CN_ * 16 * 512;
  bf16* bw = (bf16*)w;
  bf16* xz2b  = bw;  bw += (size_t)M2_ * 1024;
  bf16* xb    = bw;  bw += (size_t)M_ * D_;
  bf16* xnb2  = bw;  bw += (size_t)M2_ * DH_;
  bf16* xcvb2 = bw;  bw += (size_t)M2_ * DI_;
  bf16* ybf2  = bw;  bw += (size_t)M2_ * DI_;
  bf16* ipWb  = bw;  bw += (size_t)IPW_N;
  bf16* inWb  = bw;  bw += (size_t)INW_N;
  bf16* outWb = bw;  bw += (size_t)OUTW_N;
  bf16* opWb  = bw;  bw += (size_t)OPW_N;
  bf16* Wcomb = bw;  bw += (size_t)4 * NCP_ * 512;

  hipMemsetAsync(bar, 0, 4096, stream);
  k_mega<<<NB_, 256, 0, stream>>>(
      x, ln_g, ln_b, inW, convW, convB, xprojW, dtW, dtB, A_log, Dp, outW,
      ipW, ipB, opW, opB, fln_g, fln_b, out,
      h_cur, u_f, dtbc2, Pbuf, hend,
      xz2b, xb, xnb2, xcvb2, ybf2,
      ipWb, inWb, outWb, opWb, Wcomb, bar);
}